// Round 5
// baseline (335.811 us; speedup 1.0000x reference)
//
#include <hip/hip_runtime.h>
#include <stdint.h>

// Problem constants (B=64, P=24564, 21 classes)
#define NC 21
#define BATCH 64
#define PRI 24564
#define NROWS (BATCH * PRI)   // 1,572,096
#define SLABS 32              // slabs per batch row
#define SLABR 768             // rows per slab (last slab: 756 valid)
#define GBLK (BATCH * SLABS)  // 2048 grid-wide blocks
#define SENT 0xFFFFFFFFu      // "skip refinement" prefix sentinel

// float4 with 4-byte alignment (conf rows are 84B-strided, only dword-aligned)
typedef float f4a4 __attribute__((ext_vector_type(4), aligned(4)));

__device__ __forceinline__ float sl1f(float p, float t) {
    float d = fabsf(p - t);
    return d < 1.0f ? 0.5f * d * d : d - 0.5f;
}

// decode packed ce: sign bit = pos flag, magnitude = ce (>=0).
// key: pos -> 0x80000000 (== f2k(+0.0)); neg -> bits | 0x80000000 (== f2k(ce>=0))
__device__ __forceinline__ unsigned kdec(float v, bool* pos, float* ce) {
    unsigned u = __float_as_uint(v);
    *pos = (u >> 31) != 0;
    *ce = __uint_as_float(u & 0x7fffffffu);
    return *pos ? 0x80000000u : (u | 0x80000000u);
}
__device__ __forceinline__ unsigned kdec_key(float v) {
    unsigned u = __float_as_uint(v);
    return (u >> 31) ? 0x80000000u : (u | 0x80000000u);
}

// 256-thread block reduce (4 waves of 64). Valid on tid==0 only.
__device__ __forceinline__ double blockReduce(double v, double* sred) {
    #pragma unroll
    for (int off = 32; off > 0; off >>= 1)
        v += __shfl_down(v, off, 64);
    const int wid = threadIdx.x >> 6, lane = threadIdx.x & 63;
    __syncthreads();
    if (lane == 0) sred[wid] = v;
    __syncthreads();
    double r = 0.0;
    if (threadIdx.x == 0) r = sred[0] + sred[1] + sred[2] + sred[3];
    return r;
}

// Pass 1a: conf CE stream. No max-subtraction (|logit|<~6, fp32-safe), no
// dependent gather (g selected from registers): each 16B load feeds 4
// independent expf+add, so loads issue back-to-back. Writes ce (sign=pos),
// fused round-1 radix histogram (top 12 key bits) over nonzero-key negatives.
__global__ __launch_bounds__(256) void k_ce(
    const float* __restrict__ conf_data, const int* __restrict__ conf_t,
    float* __restrict__ ws_ce, int* __restrict__ ghist1)
{
    __shared__ int hist[4096];
    const int tid = threadIdx.x;
    const int b = blockIdx.x >> 5, s = blockIdx.x & 31;
    for (int k = tid; k < 4096; k += 256) hist[k] = 0;
    __syncthreads();
    const unsigned rb = (unsigned)b * PRI;

    int pr[3]; bool vld[3]; int ct[3];
    #pragma unroll
    for (int i = 0; i < 3; ++i) {
        int p = s * SLABR + i * 256 + tid;
        vld[i] = p < PRI;
        pr[i] = vld[i] ? p : PRI - 1;
        ct[i] = conf_t[rb + pr[i]];
    }

    #pragma unroll
    for (int i = 0; i < 3; ++i) {
        const int c = ct[i];
        const float* crow = conf_data + (long)(rb + pr[i]) * NC;
        float sum = 0.f, g = 0.f;
        #pragma unroll
        for (int j = 0; j < 5; ++j) {
            f4a4 v = ((const f4a4*)crow)[j];
            sum += __expf(v.x) + __expf(v.y) + __expf(v.z) + __expf(v.w);
            g = (4*j+0 == c) ? v.x : g;
            g = (4*j+1 == c) ? v.y : g;
            g = (4*j+2 == c) ? v.z : g;
            g = (4*j+3 == c) ? v.w : g;
        }
        float x20 = crow[20];
        sum += __expf(x20);
        g = (20 == c) ? x20 : g;
        float ce = fmaxf(__logf(sum) - g, 0.0f);
        const bool pos = c > 0;
        unsigned u = __float_as_uint(ce) | (pos ? 0x80000000u : 0u);
        if (vld[i]) {
            ws_ce[rb + pr[i]] = __uint_as_float(u);
            if (!pos) {
                unsigned key = __float_as_uint(ce) | 0x80000000u;  // f2k(ce>=0)
                if (key != 0x80000000u) atomicAdd(&hist[key >> 20], 1);
            }
        }
    }
    __syncthreads();
    for (int k = tid; k < 4096; k += 256) {
        int h = hist[k];
        if (h) atomicAdd(&ghist1[(b << 12) + k], h);
    }
}

// Pass 1b: small-array stream: smooth-L1 partials, num_pos, has_lp CE -> ws_hl.
__global__ __launch_bounds__(256) void k_small(
    const float* __restrict__ loc_data, const float* __restrict__ has_lp_data,
    const float* __restrict__ size_lp_data, const float* __restrict__ offset_data,
    const float* __restrict__ loc_t, const int* __restrict__ conf_t,
    const int* __restrict__ has_lp_t, const float* __restrict__ size_lp_t,
    const float* __restrict__ offset_t,
    float* __restrict__ ws_hl, int* __restrict__ numpos, double* __restrict__ part)
{
    __shared__ double sred[4];
    const int tid = threadIdx.x;
    const int b = blockIdx.x >> 5, s = blockIdx.x & 31;
    const unsigned rb = (unsigned)b * PRI;

    int pr[3]; bool vld[3];
    #pragma unroll
    for (int i = 0; i < 3; ++i) {
        int p = s * SLABR + i * 256 + tid;
        vld[i] = p < PRI;
        pr[i] = vld[i] ? p : PRI - 1;
    }

    double aL = 0.0, aS = 0.0, aO = 0.0;
    int myp = 0;
    #pragma unroll
    for (int i = 0; i < 3; ++i) {
        const unsigned r = rb + pr[i];
        const int c = conf_t[r];
        const int hl = has_lp_t[r];
        float4 lp = ((const float4*)loc_data)[r];
        float4 lt = ((const float4*)loc_t)[r];
        float2 sp = ((const float2*)size_lp_data)[r];
        float2 st = ((const float2*)size_lp_t)[r];
        float2 op = ((const float2*)offset_data)[r];
        float2 ot = ((const float2*)offset_t)[r];
        float2 hh = ((const float2*)has_lp_data)[r];
        const bool pos = c > 0;
        float ll = sl1f(lp.x, lt.x) + sl1f(lp.y, lt.y) + sl1f(lp.z, lt.z) + sl1f(lp.w, lt.w);
        float ls = sl1f(sp.x, st.x) + sl1f(sp.y, st.y);
        float lo = sl1f(op.x, ot.x) + sl1f(op.y, ot.y);
        const float pf = (vld[i] && pos) ? 1.f : 0.f;
        const float hf = (hl != 0) ? 1.f : 0.f;
        aL += (double)(pf * ll);
        aS += (double)(pf * hf * ls);
        aO += (double)(pf * hf * lo);
        float hm = fmaxf(hh.x, hh.y);
        float hs = __expf(hh.x - hm) + __expf(hh.y - hm);
        float hlce = fmaxf(hm + __logf(hs) - (hl != 0 ? hh.y : hh.x), 0.0f);
        if (vld[i]) ws_hl[r] = hlce;
        myp += (vld[i] && pos) ? 1 : 0;
    }
    double v;
    v = blockReduce(aL, sred); if (tid == 0) part[0 * GBLK + blockIdx.x] = v;
    v = blockReduce(aS, sred); if (tid == 0) part[1 * GBLK + blockIdx.x] = v;
    v = blockReduce(aO, sred); if (tid == 0) part[2 * GBLK + blockIdx.x] = v;
    v = blockReduce((double)myp, sred);
    if (tid == 0 && v > 0.0) atomicAdd(&numpos[b], (int)(v + 0.5));
}

// Round-0 digit pick + mode decision. M = # nonzero-key rows in batch.
// K > M  -> T = key(0), needed = K - M, refinement skipped (sentinel prefix).
__global__ __launch_bounds__(256) void k_pick0(
    const int* __restrict__ ghist1, const int* __restrict__ numpos,
    unsigned* __restrict__ prefix_io, int* __restrict__ rem_io,
    unsigned* __restrict__ selT, int* __restrict__ needed)
{
    const int b = blockIdx.x, tid = threadIdx.x;
    __shared__ int sct[256];
    __shared__ unsigned s_dig;
    __shared__ int s_rem;

    int K = 3 * numpos[b]; if (K > PRI - 1) K = PRI - 1;

    int h[16];
    const int* g = ghist1 + (b << 12) + tid * 16;
    int ctn = 0;
    #pragma unroll
    for (int j = 0; j < 16; ++j) { h[j] = g[j]; ctn += h[j]; }
    sct[tid] = ctn;
    __syncthreads();
    #pragma unroll
    for (int off = 1; off < 256; off <<= 1) {
        int v = (tid + off < 256) ? sct[tid + off] : 0;
        __syncthreads();
        sct[tid] += v;
        __syncthreads();
    }
    const int M = sct[0];

    if (K <= 0) {
        if (tid == 0) { selT[b] = 0xFFFFFFFFu; needed[b] = 0; rem_io[b] = 0; prefix_io[b] = SENT; }
        return;
    }
    if (K > M) {
        if (tid == 0) { selT[b] = 0x80000000u; needed[b] = K - M; rem_io[b] = 0; prefix_io[b] = SENT; }
        return;
    }
    const int Safter = (tid < 255) ? sct[tid + 1] : 0;
    int cum = Safter;
    #pragma unroll
    for (int j = 15; j >= 0; --j) {
        int c2 = cum + h[j];
        if (c2 >= K && cum < K) { s_dig = (unsigned)(tid * 16 + j); s_rem = K - cum; }
        cum = c2;
    }
    __syncthreads();
    if (tid == 0) { prefix_io[b] = s_dig; rem_io[b] = s_rem; }
}

// Refinement histogram (grid-wide, 1024 bins). Nulls out on sentinel prefix.
template<int MSHIFT, int BSHIFT>
__global__ __launch_bounds__(256) void k_hist(
    const float* __restrict__ ws_ce, const unsigned* __restrict__ prefix_io,
    int* __restrict__ ghist)
{
    const int b = blockIdx.x >> 5, s = blockIdx.x & 31;
    const unsigned pref = prefix_io[b];
    if (pref == SENT) return;
    __shared__ int hist[1024];
    const int tid = threadIdx.x;
    for (int k = tid; k < 1024; k += 256) hist[k] = 0;
    __syncthreads();
    #pragma unroll
    for (int i = 0; i < 3; ++i) {
        const int p = s * SLABR + i * 256 + tid;
        if (p < PRI) {
            unsigned key = kdec_key(ws_ce[(unsigned)b * PRI + p]);
            if (key != 0x80000000u && (key >> MSHIFT) == pref)
                atomicAdd(&hist[(key >> BSHIFT) & 1023], 1);
        }
    }
    __syncthreads();
    for (int k = tid; k < 1024; k += 256) {
        int h = hist[k];
        if (h) atomicAdd(&ghist[(b << 10) + k], h);
    }
}

// Refinement digit pick (1024 bins). ROUND 1 mid, ROUND 2 final.
template<int ROUND>
__global__ __launch_bounds__(256) void k_pickR(
    const int* __restrict__ ghist, unsigned* __restrict__ prefix_io,
    int* __restrict__ rem_io, unsigned* __restrict__ selT, int* __restrict__ needed)
{
    const int b = blockIdx.x, tid = threadIdx.x;
    const int rem = rem_io[b];
    if (rem <= 0) return;
    __shared__ int sct[256];
    __shared__ unsigned s_dig;
    __shared__ int s_rem;
    int h[4];
    const int* g = ghist + (b << 10) + tid * 4;
    int ctn = 0;
    #pragma unroll
    for (int j = 0; j < 4; ++j) { h[j] = g[j]; ctn += h[j]; }
    sct[tid] = ctn;
    __syncthreads();
    #pragma unroll
    for (int off = 1; off < 256; off <<= 1) {
        int v = (tid + off < 256) ? sct[tid + off] : 0;
        __syncthreads();
        sct[tid] += v;
        __syncthreads();
    }
    const int Safter = (tid < 255) ? sct[tid + 1] : 0;
    int cum = Safter;
    #pragma unroll
    for (int j = 3; j >= 0; --j) {
        int c2 = cum + h[j];
        if (c2 >= rem && cum < rem) { s_dig = (unsigned)(tid * 4 + j); s_rem = rem - cum; }
        cum = c2;
    }
    __syncthreads();
    if (tid == 0) {
        if (ROUND == 1) { prefix_io[b] = (prefix_io[b] << 10) | s_dig; rem_io[b] = s_rem; }
        else            { selT[b] = (prefix_io[b] << 10) | s_dig;      needed[b] = s_rem; }
    }
}

// Per-slab: tie count (key==T) + selected-core sums (pos || key>T)
// + tie-negative sums. One pass over ws_ce + ws_hl.
__global__ __launch_bounds__(256) void k_sel2(
    const float* __restrict__ ws_ce, const float* __restrict__ ws_hl,
    const unsigned* __restrict__ selT, int* __restrict__ cntT,
    double* __restrict__ sums)
{
    __shared__ double sred[4];
    const int tid = threadIdx.x;
    const int b = blockIdx.x >> 5, s = blockIdx.x & 31;
    const unsigned T = selT[b];
    double aC = 0.0, aH = 0.0, tC = 0.0, tH = 0.0, cc = 0.0;
    #pragma unroll
    for (int i = 0; i < 3; ++i) {
        const int p = s * SLABR + i * 256 + tid;
        if (p < PRI) {
            const unsigned r = (unsigned)b * PRI + p;
            bool pos; float ce;
            const unsigned key = kdec(ws_ce[r], &pos, &ce);
            const float hlv = ws_hl[r];
            if (pos || key > T) { aC += (double)ce; aH += (double)hlv; }
            if (key == T) {
                cc += 1.0;
                if (!pos) { tC += (double)ce; tH += (double)hlv; }
            }
        }
    }
    double v;
    v = blockReduce(aC, sred); if (tid == 0) sums[0 * GBLK + blockIdx.x] = v;
    v = blockReduce(aH, sred); if (tid == 0) sums[1 * GBLK + blockIdx.x] = v;
    v = blockReduce(tC, sred); if (tid == 0) sums[2 * GBLK + blockIdx.x] = v;
    v = blockReduce(tH, sred); if (tid == 0) sums[3 * GBLK + blockIdx.x] = v;
    v = blockReduce(cc, sred); if (tid == 0) cntT[blockIdx.x] = (int)(v + 0.5);
}

// Per batch: cutoff slab from tie counts, scan it for the needed-th tie,
// add tie-negative partials, emit (loss_c, loss_has_lp) for the batch.
__global__ __launch_bounds__(256) void k_cut(
    const float* __restrict__ ws_ce, const float* __restrict__ ws_hl,
    const unsigned* __restrict__ selT, const int* __restrict__ needed,
    const int* __restrict__ cntT, const double* __restrict__ sums,
    double* __restrict__ lossCH)
{
    const int b = blockIdx.x, tid = threadIdx.x;
    __shared__ double sred[4];
    __shared__ int scnt_s[32];
    __shared__ int s_sl, s_loc, s_found;
    __shared__ int wtot[4];
    const int need = needed[b];
    const unsigned T = selT[b];

    if (tid < 32) scnt_s[tid] = cntT[b * 32 + tid];
    __syncthreads();
    if (tid == 0) {
        int sl = 32, loc = 0, cum = 0;
        if (need > 0) {
            for (int s2 = 0; s2 < 32; ++s2) {
                int c2 = scnt_s[s2];
                if (cum + c2 >= need) { sl = s2; loc = need - cum; break; }
                cum += c2;
            }
        }
        s_sl = sl; s_loc = loc; s_found = -1;
    }
    __syncthreads();
    const int sl = s_sl, loc = s_loc;

    double aC = 0.0, aH = 0.0;
    if (tid < 32) {
        aC = sums[0 * GBLK + b * 32 + tid] + (tid < sl ? sums[2 * GBLK + b * 32 + tid] : 0.0);
        aH = sums[1 * GBLK + b * 32 + tid] + (tid < sl ? sums[3 * GBLK + b * 32 + tid] : 0.0);
    }
    double totC = blockReduce(aC, sred);
    double totH = blockReduce(aH, sred);

    if (sl < 32) {
        int run = 0;
        for (int i = 0; i < 3; ++i) {
            const int p = sl * SLABR + i * 256 + tid;
            bool eq = false;
            if (p < PRI) eq = (kdec_key(ws_ce[(unsigned)b * PRI + p]) == T);
            const unsigned long long m = __ballot(eq);
            const int lane = tid & 63, wid = tid >> 6;
            if (lane == 0) wtot[wid] = __popcll(m);
            const int mex = __popcll(m & ((1ull << lane) - 1ull));
            __syncthreads();
            int woff = 0;
            for (int w = 0; w < wid; ++w) woff += wtot[w];
            if (eq && (run + woff + mex + 1 == loc)) s_found = p;
            __syncthreads();
            run += wtot[0] + wtot[1] + wtot[2] + wtot[3];
            __syncthreads();
        }
        const int cutoff = s_found;
        double pC = 0.0, pH = 0.0;
        for (int i = 0; i < 3; ++i) {
            const int p = sl * SLABR + i * 256 + tid;
            if (p < PRI && p <= cutoff) {
                const unsigned r = (unsigned)b * PRI + p;
                bool pos; float ce;
                const unsigned key = kdec(ws_ce[r], &pos, &ce);
                if (!pos && key == T) {
                    pC += (double)ce;
                    pH += (double)ws_hl[r];
                }
            }
        }
        double v1 = blockReduce(pC, sred);
        double v2 = blockReduce(pH, sred);
        if (tid == 0) { totC += v1; totH += v2; }
    }
    if (tid == 0) { lossCH[b] = totC; lossCH[64 + b] = totH; }
}

// Sum partials, divide by N, emit 5 outputs.
__global__ __launch_bounds__(256) void k_final(
    const double* __restrict__ part, const int* __restrict__ numpos,
    const double* __restrict__ lossCH, float* __restrict__ out)
{
    __shared__ double sred[4];
    const int tid = threadIdx.x;
    double s[3];
    #pragma unroll
    for (int k = 0; k < 3; ++k) {
        double a = 0.0;
        for (int t = tid; t < GBLK; t += 256) a += part[k * GBLK + t];
        s[k] = blockReduce(a, sred);
    }
    double lc = (tid < BATCH) ? lossCH[tid] : 0.0;
    lc = blockReduce(lc, sred);
    double lh = (tid < BATCH) ? lossCH[64 + tid] : 0.0;
    lh = blockReduce(lh, sred);
    double n = (tid < BATCH) ? (double)numpos[tid] : 0.0;
    n = blockReduce(n, sred);
    if (tid == 0) {
        out[0] = (float)(s[0] / n);   // loss_l
        out[1] = (float)(lc / n);     // loss_c
        out[2] = (float)(s[1] / n);   // loss_size_lp
        out[3] = (float)(s[2] / n);   // loss_offset
        out[4] = (float)(lh / n);     // loss_has_lp
    }
}

extern "C" void kernel_launch(void* const* d_in, const int* in_sizes, int n_in,
                              void* d_out, int out_size, void* d_ws, size_t ws_size,
                              hipStream_t stream)
{
    const float* loc_data     = (const float*)d_in[0];
    const float* conf_data    = (const float*)d_in[1];
    const float* has_lp_data  = (const float*)d_in[2];
    const float* size_lp_data = (const float*)d_in[3];
    const float* offset_data  = (const float*)d_in[4];
    const float* loc_t        = (const float*)d_in[5];
    const int*   conf_t       = (const int*)d_in[6];
    const int*   has_lp_t     = (const int*)d_in[7];
    const float* size_lp_t    = (const float*)d_in[8];
    const float* offset_t     = (const float*)d_in[9];
    float* out = (float*)d_out;

    char* ws = (char*)d_ws;
    int* numpos      = (int*)(ws + 0);           // 64 int
    unsigned* selT   = (unsigned*)(ws + 256);    // 64 u32
    int* needed      = (int*)(ws + 512);         // 64 int
    unsigned* prefix = (unsigned*)(ws + 768);    // 64 u32
    int* rem         = (int*)(ws + 1024);        // 64 int
    int* cntT        = (int*)(ws + 1536);        // 2048 int (8 KB)
    double* part     = (double*)(ws + 16384);    // 3*2048 doubles (48 KB)
    double* sums     = (double*)(ws + 65536);    // 4*2048 doubles (64 KB)
    double* lossCH   = (double*)(ws + 131072);   // 128 doubles
    int* ghist1      = (int*)(ws + 132096);      // 64*4096 int (1 MB)
    int* ghist2      = (int*)(ws + 1180672);     // 64*1024 int (256 KB)
    int* ghist3      = (int*)(ws + 1442816);     // 64*1024 int (256 KB)
    float* ws_ce     = (float*)(ws + 1704960);   // NROWS floats (~6.3 MB)
    float* ws_hl     = (float*)(ws + 7993344);   // NROWS floats (~6.3 MB)

    hipMemsetAsync(ws, 0, 256, stream);                  // numpos
    hipMemsetAsync(ws + 132096, 0, 1572864, stream);     // ghist1..3

    k_ce<<<GBLK, 256, 0, stream>>>(conf_data, conf_t, ws_ce, ghist1);
    k_small<<<GBLK, 256, 0, stream>>>(loc_data, has_lp_data, size_lp_data, offset_data,
                                      loc_t, conf_t, has_lp_t, size_lp_t, offset_t,
                                      ws_hl, numpos, part);
    k_pick0<<<BATCH, 256, 0, stream>>>(ghist1, numpos, prefix, rem, selT, needed);
    k_hist<20, 10><<<GBLK, 256, 0, stream>>>(ws_ce, prefix, ghist2);
    k_pickR<1><<<BATCH, 256, 0, stream>>>(ghist2, prefix, rem, selT, needed);
    k_hist<10, 0><<<GBLK, 256, 0, stream>>>(ws_ce, prefix, ghist3);
    k_pickR<2><<<BATCH, 256, 0, stream>>>(ghist3, prefix, rem, selT, needed);
    k_sel2<<<GBLK, 256, 0, stream>>>(ws_ce, ws_hl, selT, cntT, sums);
    k_cut<<<BATCH, 256, 0, stream>>>(ws_ce, ws_hl, selT, needed, cntT, sums, lossCH);
    k_final<<<1, 256, 0, stream>>>(part, numpos, lossCH, out);
}